// Round 5
// baseline (9201.913 us; speedup 1.0000x reference)
//
#include <hip/hip_runtime.h>

// 3-layer LSTM, B=256, T=2048, H=128 — v4b: v4 with the inline-asm operand
// type fixed (HIP float4 struct can't bind to "v" constraint; use
// ext_vector_type f32x4 which lowers to a native v[4] tuple).
//
// Design (unchanged from v4): layer-per-block pipeline (48 blocks =
// 16 groups x 3 layers), seq-batched MFMA (full matrix-pipe util),
// (1) cache-op-free MALL handshake: producer stores chunk + flag with
//     sc0 sc1 (bypass L1/L2 -> Infinity Cache, device-coherent); consumer
//     polls flag sc0 sc1, reads data with PLAIN loads (slot lines always
//     cold in consumer L1/L2 -> miss to MALL -> fresh).
// (2) proj and rec as independent 4-deep MFMA chains (issue-bound).
// (3) wih streamed from L2 per step; whh VGPR-resident (64 VGPR).
// Watch: absmax blowup => sc-bypass coherence wrong => revert to fences.

#define HDIM 128
#define TDIM 2048
#define NB 16       // sequences per group (MFMA rows)
#define NG 16       // groups
#define CH 16       // chunk length (timesteps)
#define NCH 128     // chunks per sequence
#define NT 512      // 8 waves

typedef _Float16 half8_t __attribute__((ext_vector_type(8)));
typedef float f32x4 __attribute__((ext_vector_type(4)));

__device__ __forceinline__ f32x4 mfma16(half8_t a, half8_t b, f32x4 c) {
    return __builtin_amdgcn_mfma_f32_16x16x32_f16(a, b, c, 0, 0, 0);
}

// Workgroup barrier WITHOUT vmcnt(0) drain: LDS visibility only.
__device__ __forceinline__ void fast_barrier() {
    asm volatile("s_waitcnt lgkmcnt(0)\n\ts_barrier" ::: "memory");
}

__device__ __forceinline__ float sigm_f(float x) {
    return __builtin_amdgcn_rcpf(1.0f + __expf(-x));
}
__device__ __forceinline__ float tanh_f(float x) {
    return fmaf(-2.0f, __builtin_amdgcn_rcpf(1.0f + __expf(2.0f * x)), 1.0f);
}

// One-time fp32 -> fp16 weight conversion + flag zeroing.
// Segments of 65536: [Whh0,Wih1,Whh1,Wih2,Whh2]
__global__ __launch_bounds__(256)
void convert_w(const float* __restrict__ Whh0, const float* __restrict__ Wih1,
               const float* __restrict__ Whh1, const float* __restrict__ Wih2,
               const float* __restrict__ Whh2, _Float16* __restrict__ dst,
               int* __restrict__ flags) {
    int i = blockIdx.x * 256 + threadIdx.x;
    if (i < 2 * NG * NCH) flags[i] = 0;
    int seg = i >> 16, off = i & 65535;
    const float* s = (seg == 0) ? Whh0 : (seg == 1) ? Wih1 : (seg == 2) ? Whh1
                   : (seg == 3) ? Wih2 : Whh2;
    dst[i] = (_Float16)s[off];
}

__global__ __launch_bounds__(NT, 2)
void lstm3_pipe(const float* __restrict__ x,   const float* __restrict__ Wih0,
                const float* __restrict__ bih0, const float* __restrict__ bhh0,
                const float* __restrict__ bih1, const float* __restrict__ bhh1,
                const float* __restrict__ bih2, const float* __restrict__ bhh2,
                const float* __restrict__ fc1w, const float* __restrict__ fc1b,
                const float* __restrict__ fc2w, const float* __restrict__ fc2b,
                float* __restrict__ out,
                _Float16* __restrict__ hbuf, const _Float16* __restrict__ wbuf,
                int* __restrict__ flags)
{
    // own h window (one chunk, swizzled slices) + staged prev-layer chunk
    __shared__ __align__(16) _Float16 hown[CH * NB * HDIM];  // 64 KB
    __shared__ __align__(16) _Float16 hst [CH * NB * HDIM];  // 64 KB
    __shared__ float x_s[CH][NB];                            // layer0 input
    __shared__ float z_s[NB][64];                            // FC tail
    __shared__ float hfin[NB][HDIM];                         // de-swizzled hT

    const int tid = threadIdx.x;
    const int ln = tid & 63, wv = tid >> 6;   // wave j owns units [16j,16j+16)
    const int c = ln & 15, p = ln >> 4;       // col-in-tile / row-quadrant
    const int L = blockIdx.x >> 4;            // layer 0..2 (layer0 = bids 0..15)
    const int g = blockIdx.x & 15;            // seq group

    // ---- resident Whh fragments (64 VGPR). Wih streamed per step (L2-hot).
    const _Float16* whh = wbuf + (size_t)((L == 0) ? 0 : (L == 1) ? 2 : 4) * 65536;
    const _Float16* wih = wbuf + (size_t)((L == 1) ? 1 : 3) * 65536;  // L0: unused
    half8_t whh_f[4][4];
#pragma unroll
    for (int q = 0; q < 4; ++q)
#pragma unroll
        for (int m = 0; m < 4; ++m)
            whh_f[q][m] = *(const half8_t*)(whh + (size_t)(q*HDIM + wv*16 + c)*HDIM + m*32 + p*8);
    // per-lane wih base: frag(q,m) at wihL + q*HDIM*HDIM + m*32
    const _Float16* wihL = wih + (size_t)(wv*16 + c)*HDIM + p*8;

    const float* bihL = (L == 0) ? bih0 : (L == 1) ? bih1 : bih2;
    const float* bhhL = (L == 0) ? bhh0 : (L == 1) ? bhh1 : bhh2;
    const int u = wv * 16 + c;                // this lane's unit
    float bias[4], w0[4];
#pragma unroll
    for (int q = 0; q < 4; ++q) {
        bias[q] = bihL[q*HDIM + u] + bhhL[q*HDIM + u];
        w0[q] = (L == 0) ? Wih0[q*HDIM + u] : 0.0f;
    }

    // swizzled offsets: slice layout [seq][u ^ 8*(seq&7)]
    int roff[4], woff[4];
#pragma unroll
    for (int m = 0; m < 4; ++m)
        roff[m] = c*HDIM + ((32*m + 8*p) ^ (8*(c & 7)));
#pragma unroll
    for (int r = 0; r < 4; ++r) {
        int seq = p*4 + r;
        woff[r] = seq*HDIM + (u ^ (8*(seq & 7)));
    }

    // h(-1) = 0: zero slice 15 (read as "prev" at chunk 0, step 0)
    for (int i = tid; i < NB*HDIM/2; i += NT)
        ((int*)(hown + 15*NB*HDIM))[i] = 0;
    float cc[4] = {0.f, 0.f, 0.f, 0.f};
    __syncthreads();

    int* fprod = flags + (L*NG + g)*NCH;          // set by this block (L<2)
    const int* fcons = flags + ((L-1)*NG + g)*NCH;// polled (L>0)
    const float* xb = x + (size_t)(g*NB)*TDIM;

#pragma unroll 1
    for (int s = 0; s < NCH; ++s) {
        _Float16* gch = hbuf + ((size_t)(g*NCH + s) << 15);   // 64 KB slot

        if (L == 0) {
            if (tid < CH*NB)
                x_s[tid >> 4][tid & 15] = xb[(size_t)(tid & 15)*TDIM + s*CH + (tid >> 4)];
        } else {
            // poll producer flag with L1/L2-bypassing loads (no cache inv ops)
            if (tid == 0) {
                const int* fp = fcons + s;
                int f;
                while (1) {
                    asm volatile("global_load_dword %0, %1, off sc0 sc1\n\t"
                                 "s_waitcnt vmcnt(0)"
                                 : "=v"(f) : "v"(fp) : "memory");
                    if (f) break;
                    __builtin_amdgcn_s_sleep(2);
                }
            }
            __syncthreads();
            // stage chunk: plain loads (slot cold in this block's L1/L2 -> MALL)
            const f32x4* gsrc = (const f32x4*)gch;
            f32x4* dv = (f32x4*)hst;
#pragma unroll
            for (int k2 = 0; k2 < 8; ++k2) dv[k2*NT + tid] = gsrc[k2*NT + tid];
        }
        fast_barrier();   // x_s / hst visible

#pragma unroll 1
        for (int tt = 0; tt < CH; ++tt) {
            const int tp = (tt + CH - 1) & 15;
            const _Float16* rsl = hown + tp*(NB*HDIM);
            // rec A-frags: A[row=seq=c][k = m*32+p*8+e] from swizzled slice
            half8_t A0 = *(const half8_t*)(rsl + roff[0]);
            half8_t A1 = *(const half8_t*)(rsl + roff[1]);
            half8_t A2 = *(const half8_t*)(rsl + roff[2]);
            half8_t A3 = *(const half8_t*)(rsl + roff[3]);

            f32x4 acc[4], pac[4];
            // rec: 4 independent 4-deep chains on resident whh
#pragma unroll
            for (int q = 0; q < 4; ++q) {
                f32x4 a = {0.f, 0.f, 0.f, 0.f};
                a = mfma16(A0, whh_f[q][0], a);
                a = mfma16(A1, whh_f[q][1], a);
                a = mfma16(A2, whh_f[q][2], a);
                a = mfma16(A3, whh_f[q][3], a);
                acc[q] = a;
            }
            if (L > 0) {
                const _Float16* psl = hst + tt*(NB*HDIM);
                half8_t P0 = *(const half8_t*)(psl + roff[0]);
                half8_t P1 = *(const half8_t*)(psl + roff[1]);
                half8_t P2 = *(const half8_t*)(psl + roff[2]);
                half8_t P3 = *(const half8_t*)(psl + roff[3]);
                // proj: 4 more independent chains, wih streamed (L2-hot, same
                // addresses every step)
#pragma unroll
                for (int q = 0; q < 4; ++q) {
                    const _Float16* wq = wihL + q*(HDIM*HDIM);
                    half8_t B0 = *(const half8_t*)(wq);
                    half8_t B1 = *(const half8_t*)(wq + 32);
                    half8_t B2 = *(const half8_t*)(wq + 64);
                    half8_t B3 = *(const half8_t*)(wq + 96);
                    f32x4 a = {0.f, 0.f, 0.f, 0.f};
                    a = mfma16(P0, B0, a);
                    a = mfma16(P1, B1, a);
                    a = mfma16(P2, B2, a);
                    a = mfma16(P3, B3, a);
                    pac[q] = a;
                }
            }

            _Float16* wsl = hown + tt*(NB*HDIM);
#pragma unroll
            for (int r = 0; r < 4; ++r) {
                float pi = acc[0][r] + bias[0];
                float pf = acc[1][r] + bias[1];
                float pg = acc[2][r] + bias[2];
                float po = acc[3][r] + bias[3];
                if (L > 0) {
                    pi += pac[0][r]; pf += pac[1][r];
                    pg += pac[2][r]; po += pac[3][r];
                } else {
                    float xr = x_s[tt][p*4 + r];
                    pi = fmaf(xr, w0[0], pi); pf = fmaf(xr, w0[1], pf);
                    pg = fmaf(xr, w0[2], pg); po = fmaf(xr, w0[3], po);
                }
                float ig = sigm_f(pi), fg = sigm_f(pf);
                float gg = tanh_f(pg), og = sigm_f(po);
                cc[r] = fmaf(fg, cc[r], ig * gg);
                wsl[woff[r]] = (_Float16)(og * tanh_f(cc[r]));
            }
            fast_barrier();   // h(t) visible for step t+1
        }

        if (L < 2) {
            // publish chunk: sc0 sc1 stores bypass L1/L2 -> Infinity Cache
            // (device-coherent); per-thread vmcnt drain; barrier; flag store.
            const f32x4* sv = (const f32x4*)hown;
#pragma unroll
            for (int k2 = 0; k2 < 8; ++k2) {
                f32x4 v = sv[k2*NT + tid];
                f32x4* gp = (f32x4*)gch + k2*NT + tid;
                asm volatile("global_store_dwordx4 %0, %1, off sc0 sc1"
                             :: "v"(gp), "v"(v) : "memory");
            }
            asm volatile("s_waitcnt vmcnt(0)" ::: "memory");  // asm stores are
            __syncthreads();          // invisible to the compiler's waitcnt
            if (tid == 0) {
                int one = 1;
                int* fp = fprod + s;
                asm volatile("global_store_dword %0, %1, off sc0 sc1"
                             :: "v"(fp), "v"(one) : "memory");
            }
        }
    }

    // ---- FC head (layer-2 blocks): hT = hown slice 15 (chunk 127) ----
    if (L == 2) {
        __syncthreads();
        for (int i = tid; i < NB*HDIM; i += NT) {
            int seq = i >> 7, uu = i & 127;
            hfin[seq][uu] = (float)hown[15*NB*HDIM + seq*HDIM + (uu ^ (8*(seq & 7)))];
        }
        __syncthreads();
        for (int d = tid; d < NB*64; d += NT) {
            int seq = d >> 6, un = d & 63;
            const float4* w4 = (const float4*)(fc1w + un*HDIM);
            const float4* h4 = (const float4*)hfin[seq];
            float sacc = fc1b[un];
#pragma unroll
            for (int k2 = 0; k2 < 32; ++k2) {
                float4 a = w4[k2], bb = h4[k2];
                sacc += a.x*bb.x + a.y*bb.y + a.z*bb.z + a.w*bb.w;
            }
            z_s[seq][un] = fmaxf(sacc, 0.0f);
        }
        __syncthreads();
        for (int d = tid; d < NB*5; d += NT) {
            int seq = d / 5, o = d - seq*5;
            const float* w = fc2w + o*64;
            float sacc = fc2b[o];
#pragma unroll
            for (int k2 = 0; k2 < 64; ++k2) sacc += w[k2] * z_s[seq][k2];
            out[(size_t)(g*NB + seq)*5 + o] = sacc;
        }
    }
}

extern "C" void kernel_launch(void* const* d_in, const int* in_sizes, int n_in,
                              void* d_out, int out_size, void* d_ws, size_t ws_size,
                              hipStream_t stream) {
    (void)in_sizes; (void)n_in; (void)out_size; (void)ws_size;
    const float* x    = (const float*)d_in[0];
    const float* Wih0 = (const float*)d_in[1];
    const float* Whh0 = (const float*)d_in[2];
    const float* bih0 = (const float*)d_in[3];
    const float* bhh0 = (const float*)d_in[4];
    const float* Wih1 = (const float*)d_in[5];
    const float* Whh1 = (const float*)d_in[6];
    const float* bih1 = (const float*)d_in[7];
    const float* bhh1 = (const float*)d_in[8];
    const float* Wih2 = (const float*)d_in[9];
    const float* Whh2 = (const float*)d_in[10];
    const float* bih2 = (const float*)d_in[11];
    const float* bhh2 = (const float*)d_in[12];
    const float* fc1w = (const float*)d_in[13];
    const float* fc1b = (const float*)d_in[14];
    const float* fc2w = (const float*)d_in[15];
    const float* fc2b = (const float*)d_in[16];
    float* out = (float*)d_out;

    _Float16* hbuf = (_Float16*)d_ws;                    // 128 MB chunk slots
    _Float16* wbuf = hbuf + (size_t)67108864;            // fp16 weights (640 KB)
    int* flags = (int*)(wbuf + (size_t)5*65536);         // 2*16*128 ints (16 KB)

    hipLaunchKernelGGL(convert_w, dim3(1280), dim3(256), 0, stream,
                       Whh0, Wih1, Whh1, Wih2, Whh2, wbuf, flags);
    hipLaunchKernelGGL(lstm3_pipe, dim3(3*NG), dim3(NT), 0, stream,
                       x, Wih0, bih0, bhh0, bih1, bhh1, bih2, bhh2,
                       fc1w, fc1b, fc2w, fc2b, out, hbuf, wbuf, flags);
}